// Round 7
// baseline (92.232 us; speedup 1.0000x reference)
//
#include <hip/hip_runtime.h>
#include <math.h>

#define NQ 12
#define NL 4
#define NC 10
#define NB 512
#define BN_EPS 1e-5f

typedef float v2f __attribute__((ext_vector_type(2)));

// Packed complex 2x2 butterfly. Constants pre-paired:
// c0={m0,m0} c1={-m1,m1} c2={m2,m2} c3={-m3,m3} (row 0), c4..c7 row 1.
__device__ __forceinline__ void bfly(v2f& A, v2f& B,
    v2f c0, v2f c1, v2f c2, v2f c3, v2f c4, v2f c5, v2f c6, v2f c7)
{
    const v2f As = A.yx, Bs = B.yx;
    const v2f An = __builtin_elementwise_fma(c0, A,
                   __builtin_elementwise_fma(c1, As,
                   __builtin_elementwise_fma(c2, B, c3 * Bs)));
    const v2f Bn = __builtin_elementwise_fma(c4, A,
                   __builtin_elementwise_fma(c5, As,
                   __builtin_elementwise_fma(c6, B, c7 * Bs)));
    A = An; B = Bn;
}

// Precompute all 512x48 fused (Rot*RY) gate matrices into d_ws (pre-paired).
__global__ __launch_bounds__(256) void gates_kernel(
    const float* __restrict__ x, const float* __restrict__ w,
    float* __restrict__ gates)
{
    const int idx = blockIdx.x * 256 + threadIdx.x;
    if (idx >= NB * 48) return;
    const int b = idx / 48, g = idx % 48;
    const int q = g % NQ;
    const float xq = 0.5f * x[b*NQ + q];
    const float cx = cosf(xq), sx = sinf(xq);
    const int wi = g*3;
    const float phi = w[wi], tht = w[wi+1], om = w[wi+2];
    const float ct = cosf(0.5f*tht), st = sinf(0.5f*tht);
    const float aa = 0.5f*(phi + om), dd = 0.5f*(phi - om);
    const float ca = cosf(aa), sa = sinf(aa);
    const float cd = cosf(dd), sd = sinf(dd);
    const float u00r =  ca*ct, u00i = -sa*ct;
    const float u01r = -cd*st, u01i = -sd*st;
    const float u10r =  cd*st, u10i = -sd*st;
    const float u11r =  ca*ct, u11i =  sa*ct;
    const float m00r = u00r*cx + u01r*sx, m00i = u00i*cx + u01i*sx;
    const float m01r = u01r*cx - u00r*sx, m01i = u01i*cx - u00i*sx;
    const float m10r = u10r*cx + u11r*sx, m10i = u10i*cx + u11i*sx;
    const float m11r = u11r*cx - u10r*sx, m11i = u11i*cx - u10i*sx;
    float* gp = gates + (size_t)idx * 16;
    gp[0]  =  m00r; gp[1]  = m00r;  gp[2]  = -m00i; gp[3]  = m00i;
    gp[4]  =  m01r; gp[5]  = m01r;  gp[6]  = -m01i; gp[7]  = m01i;
    gp[8]  =  m10r; gp[9]  = m10r;  gp[10] = -m10i; gp[11] = m10i;
    gp[12] =  m11r; gp[13] = m11r;  gp[14] = -m11i; gp[15] = m11i;
}

// Register-tiled VQC (round-5 structure): one block per sample; 16 amps
// (4 local qubits) per thread; 11 double-buffered single-barrier transitions.
// LDS slot: slot(t,r)=(r<<8)|(phi(t)^17r). Ring-CNOT fused into C->A' writes
// + readout signs. Gate constants come from global via block-uniform pointer
// (uniformity analysis -> s_load, SMEM pipe) instead of LDS broadcasts.
__global__ __launch_bounds__(256) void vqc_kernel(
    const float* __restrict__ gates, const float* __restrict__ bias,
    float* __restrict__ probs)
{
    __shared__ v2f buf[2][4096];                  // 2 x 32 KB staging
    __shared__ float red[4*NC];

    const int b = blockIdx.x;
    const int t = threadIdx.x;
    const v2f* __restrict__ gcp = (const v2f*)(gates + (size_t)b * 768);

    // ---- registers: stage-A layout, global i = (r<<8)|t ----
    v2f a[16];
    #pragma unroll
    for (int r = 0; r < 16; ++r) a[r] = (v2f){0.f, 0.f};
    if (t == 0) a[0].x = 1.f;

    const int tl = t & 15, th4 = t >> 4;
    const int phit = t ^ th4;                       // phi(t)
    const int vAB = (th4 << 8) | (tl ^ (th4 * 17)); // A->B write base
    const int wBC = (tl << 8) | ((th4 ^ tl) * 17);  // B->C write base

    // ---- C->A' (CNOT ring) per-thread constants ----
    const unsigned b0_ = t & 1u, b1_ = (t>>1)&1u, b2_ = (t>>2)&1u, b3_ = (t>>3)&1u,
                   b4_ = (t>>4)&1u, b5_ = (t>>5)&1u, b6_ = (t>>6)&1u, b7_ = (t>>7)&1u;
    const unsigned P7 = b7_, P6 = P7^b6_, P5 = P6^b5_, P4 = P5^b4_,
                   P3 = P4^b3_, P2 = P3^b2_, P1 = P2^b1_, T = P1^b0_;  // Pk = parity(t>>k)
    const unsigned base_j = ((T ^ b7_) << 11) | (P6 << 10) | (P5 << 9) | (P4 << 8)
                          | (P3 << 7) | (P2 << 6) | (P1 << 5) | (T << 4)
                          | (T ? 0xFu : 0u);
    const unsigned rA = (base_j >> 8) & 15u;
    const unsigned tA = base_j & 255u;
    const unsigned baseCA = (rA << 8) | ((tA ^ (tA >> 4)) ^ (rA * 17u));

    // Gates in ascending bit order (1,2,4,8): first gate after a transition
    // needs only a[0],a[1]. Bit (1<<g) -> matrix gcp[((base)+3-g)*8 ..].
    #define STAGE(base) \
        _Pragma("unroll") \
        for (int g = 0; g < 4; ++g) { \
            const v2f* cp = gcp + ((base) + 3 - g) * 8; \
            const v2f c0=cp[0],c1=cp[1],c2=cp[2],c3=cp[3], \
                      c4=cp[4],c5=cp[5],c6=cp[6],c7=cp[7]; \
            const int bit = 1 << g; \
            _Pragma("unroll") \
            for (int r0 = 0; r0 < 16; ++r0) \
                if (!(r0 & bit)) bfly(a[r0], a[r0|bit], c0,c1,c2,c3,c4,c5,c6,c7); \
        }

    int pb = 0;  // staging buffer parity (folds under full unroll)
    #pragma unroll
    for (int l = 0; l < NL; ++l) {
        // ---- stage 0: qubits 0..3 ----
        STAGE(l*12)
        // ---- transition A->B (single barrier, double-buffered) ----
        {
            v2f* bp = buf[pb]; pb ^= 1;
            #pragma unroll
            for (int r = 0; r < 16; ++r) bp[vAB ^ (r*17)] = a[r];
            __syncthreads();
            #pragma unroll
            for (int r = 0; r < 16; ++r) a[r] = bp[(r<<8) | (phit ^ (r*17))];
        }

        // ---- stage 1: qubits 4..7 ----
        STAGE(l*12 + 4)
        // ---- transition B->C ----
        {
            v2f* bp = buf[pb]; pb ^= 1;
            #pragma unroll
            for (int r = 0; r < 16; ++r) bp[wBC ^ r] = a[r];
            __syncthreads();
            #pragma unroll
            for (int r = 0; r < 16; ++r) a[r] = bp[(r<<8) | (phit ^ (r*17))];
        }

        // ---- stage 2: qubits 8..11 ----
        STAGE(l*12 + 8)
        if (l < NL-1) {
            // ---- transition C->A' with ring-CNOT permutation fused ----
            v2f* bp = buf[pb]; pb ^= 1;
            #pragma unroll
            for (int r = 0; r < 16; ++r) {
                const unsigned k3 = (r>>3)&1u;
                const unsigned k2 = k3 ^ ((r>>2)&1u);
                const unsigned k1 = k2 ^ ((r>>1)&1u);
                const unsigned k0 = k1 ^ (r&1u);           // = par(r)
                const unsigned K  = (k3<<3)|(k2<<2)|(k1<<1)|k0;
                const unsigned d  = K ^ (k0 * 0x888u);     // compile-time per r
                bp[baseCA ^ d] = a[r];
            }
            __syncthreads();
            #pragma unroll
            for (int r = 0; r < 16; ++r) a[r] = bp[(r<<8) | (phit ^ (r*17))];
        }
    }

    // ---- readout: signs are bits of j = M(i), i = (t<<4)|r ----
    const float S0 = (T ^ b7_) ? -1.f : 1.f;  // j_11 base (flip by par(r))
    const float S1 = P6 ? -1.f : 1.f;         // j_10
    const float S2 = P5 ? -1.f : 1.f;         // j_9
    const float S3 = P4 ? -1.f : 1.f;         // j_8
    const float S4 = P3 ? -1.f : 1.f;         // j_7
    const float S5 = P2 ? -1.f : 1.f;         // j_6
    const float S6 = P1 ? -1.f : 1.f;         // j_5
    const float S7 = T  ? -1.f : 1.f;         // j_4
    const float S8 = T  ? -1.f : 1.f;         // j_3 base (flip by r3)
    const float S9 = T  ? -1.f : 1.f;         // j_2 base (flip by r3^r2)

    float acc[NC];
    #pragma unroll
    for (int c = 0; c < NC; ++c) acc[c] = 0.f;
    #pragma unroll
    for (int r = 0; r < 16; ++r) {
        const float p = a[r].x*a[r].x + a[r].y*a[r].y;
        const int r3 = (r>>3)&1, r2 = (r>>2)&1, r1 = (r>>1)&1, r0b = r&1;
        const int par = r3 ^ r2 ^ r1 ^ r0b;
        acc[0] += (par        ? -S0 : S0) * p;
        acc[1] += S1 * p;
        acc[2] += S2 * p;
        acc[3] += S3 * p;
        acc[4] += S4 * p;
        acc[5] += S5 * p;
        acc[6] += S6 * p;
        acc[7] += S7 * p;
        acc[8] += (r3         ? -S8 : S8) * p;
        acc[9] += ((r3 ^ r2)  ? -S9 : S9) * p;
    }
    #pragma unroll
    for (int off = 32; off >= 1; off >>= 1) {
        #pragma unroll
        for (int c = 0; c < NC; ++c)
            acc[c] += __shfl_down(acc[c], off, 64);
    }
    const int wave = t >> 6, lane = t & 63;
    if (lane == 0) {
        #pragma unroll
        for (int c = 0; c < NC; ++c) red[wave*NC + c] = acc[c];
    }
    __syncthreads();
    if (t == 0) {
        float ez[NC];
        float mx = -1e30f;
        #pragma unroll
        for (int c = 0; c < NC; ++c) {
            ez[c] = red[c] + red[NC + c] + red[2*NC + c] + red[3*NC + c] + bias[c];
            mx = fmaxf(mx, ez[c]);
        }
        float sum = 0.f;
        #pragma unroll
        for (int c = 0; c < NC; ++c) { ez[c] = expf(ez[c] - mx); sum += ez[c]; }
        const float inv = 1.f / sum;
        #pragma unroll
        for (int c = 0; c < NC; ++c) probs[b*NC + c] = ez[c] * inv;
    }
}

// BatchNorm1d (training mode, biased var) over the batch dim, in place on d_out.
__global__ __launch_bounds__(256) void bn_kernel(
    float* __restrict__ probs, const float* __restrict__ gamma,
    const float* __restrict__ beta)
{
    const int c = blockIdx.x;
    const int t = threadIdx.x;
    const float v0 = probs[t*NC + c];
    const float v1 = probs[(t + 256)*NC + c];
    float s  = v0 + v1;
    float ss = v0*v0 + v1*v1;
    #pragma unroll
    for (int off = 32; off >= 1; off >>= 1) {
        s  += __shfl_down(s,  off, 64);
        ss += __shfl_down(ss, off, 64);
    }
    __shared__ float sm[8];
    __shared__ float stat[2];
    const int wave = t >> 6, lane = t & 63;
    if (lane == 0) { sm[wave] = s; sm[4 + wave] = ss; }
    __syncthreads();
    if (t == 0) {
        const float S  = sm[0] + sm[1] + sm[2] + sm[3];
        const float SS = sm[4] + sm[5] + sm[6] + sm[7];
        const float mu  = S * (1.f/512.f);
        const float var = SS * (1.f/512.f) - mu*mu;
        stat[0] = mu;
        stat[1] = 1.f / sqrtf(var + BN_EPS);
    }
    __syncthreads();
    const float mu = stat[0], inv = stat[1];
    const float g = gamma[c], bt = beta[c];
    probs[t*NC + c]         = (v0 - mu) * inv * g + bt;
    probs[(t + 256)*NC + c] = (v1 - mu) * inv * g + bt;
}

extern "C" void kernel_launch(void* const* d_in, const int* in_sizes, int n_in,
                              void* d_out, int out_size, void* d_ws, size_t ws_size,
                              hipStream_t stream) {
    const float* x     = (const float*)d_in[0];   // (512, 12)
    const float* w     = (const float*)d_in[1];   // (4, 12, 3)
    const float* bias  = (const float*)d_in[2];   // (10,)
    const float* gamma = (const float*)d_in[3];   // (10,)
    const float* beta  = (const float*)d_in[4];   // (10,)
    float* out   = (float*)d_out;                 // (512, 10) float32
    float* gates = (float*)d_ws;                  // 512*48*16 floats = 1.57 MB

    gates_kernel<<<(NB*48 + 255)/256, 256, 0, stream>>>(x, w, gates);
    vqc_kernel<<<NB, 256, 0, stream>>>(gates, bias, out);
    bn_kernel<<<NC, 256, 0, stream>>>(out, gamma, beta);
}

// Round 8
// 91.104 us; speedup vs baseline: 1.0124x; 1.0124x over previous
//
#include <hip/hip_runtime.h>
#include <math.h>

#define NQ 12
#define NL 4
#define NC 10
#define NB 512
#define BN_EPS 1e-5f

typedef float v2f __attribute__((ext_vector_type(2)));

// Packed complex 2x2 butterfly. Constants pre-paired:
// c0={m0,m0} c1={-m1,m1} c2={m2,m2} c3={-m3,m3} (row 0), c4..c7 row 1.
__device__ __forceinline__ void bfly(v2f& A, v2f& B,
    v2f c0, v2f c1, v2f c2, v2f c3, v2f c4, v2f c5, v2f c6, v2f c7)
{
    const v2f As = A.yx, Bs = B.yx;
    const v2f An = __builtin_elementwise_fma(c0, A,
                   __builtin_elementwise_fma(c1, As,
                   __builtin_elementwise_fma(c2, B, c3 * Bs)));
    const v2f Bn = __builtin_elementwise_fma(c4, A,
                   __builtin_elementwise_fma(c5, As,
                   __builtin_elementwise_fma(c6, B, c7 * Bs)));
    A = An; B = Bn;
}

// Register-tiled VQC (round-5 structure, best measured): one block per sample;
// 16 amps (4 local qubits) per thread; 11 double-buffered single-barrier
// transitions; gm in LDS; ring-CNOT fused into C->A' writes + readout signs.
// BatchNorm fused via last-arriver block: after writing its softmax row each
// block fences + bumps a counter in d_ws; the block whose atomicAdd returns
// old&511==511 (exactly one in any 512-window, any initial value) runs BN.
__global__ __launch_bounds__(256) void vqc_kernel(
    const float* __restrict__ x, const float* __restrict__ w,
    const float* __restrict__ bias, const float* __restrict__ gamma,
    const float* __restrict__ beta, float* __restrict__ probs,
    unsigned* __restrict__ cnt)
{
    __shared__ v2f buf[2][4096];                  // 2 x 32 KB staging
    __shared__ __align__(16) float gm[48][16];    // 48 gates x 8 paired consts
    __shared__ float red[80];                     // wave partials (max 4x20)
    __shared__ float stats[2*NC];
    __shared__ int sh_last;

    const int b = blockIdx.x;
    const int t = threadIdx.x;

    // ---- one-time: all 48 fused (Rot * RY) matrices, pre-paired/negated ----
    if (t < 48) {
        const int l = t / NQ, q = t % NQ;
        const float xq = 0.5f * x[b*NQ + q];
        const float cx = cosf(xq), sx = sinf(xq);
        const int wi = (l*NQ + q)*3;
        const float phi = w[wi], tht = w[wi+1], om = w[wi+2];
        const float ct = cosf(0.5f*tht), st = sinf(0.5f*tht);
        const float aa = 0.5f*(phi + om), dd = 0.5f*(phi - om);
        const float ca = cosf(aa), sa = sinf(aa);
        const float cd = cosf(dd), sd = sinf(dd);
        const float u00r =  ca*ct, u00i = -sa*ct;
        const float u01r = -cd*st, u01i = -sd*st;
        const float u10r =  cd*st, u10i = -sd*st;
        const float u11r =  ca*ct, u11i =  sa*ct;
        const float m00r = u00r*cx + u01r*sx, m00i = u00i*cx + u01i*sx;
        const float m01r = u01r*cx - u00r*sx, m01i = u01i*cx - u00i*sx;
        const float m10r = u10r*cx + u11r*sx, m10i = u10i*cx + u11i*sx;
        const float m11r = u11r*cx - u10r*sx, m11i = u11i*cx - u10i*sx;
        float* gp = gm[t];
        gp[0]  =  m00r; gp[1]  = m00r;
        gp[2]  = -m00i; gp[3]  = m00i;
        gp[4]  =  m01r; gp[5]  = m01r;
        gp[6]  = -m01i; gp[7]  = m01i;
        gp[8]  =  m10r; gp[9]  = m10r;
        gp[10] = -m10i; gp[11] = m10i;
        gp[12] =  m11r; gp[13] = m11r;
        gp[14] = -m11i; gp[15] = m11i;
    }
    __syncthreads();

    // ---- registers: stage-A layout, global i = (r<<8)|t ----
    v2f a[16];
    #pragma unroll
    for (int r = 0; r < 16; ++r) a[r] = (v2f){0.f, 0.f};
    if (t == 0) a[0].x = 1.f;

    const int tl = t & 15, th4 = t >> 4;
    const int phit = t ^ th4;                       // phi(t)
    const int vAB = (th4 << 8) | (tl ^ (th4 * 17)); // A->B write base
    const int wBC = (tl << 8) | ((th4 ^ tl) * 17);  // B->C write base

    // ---- C->A' (CNOT ring) per-thread constants ----
    const unsigned b0_ = t & 1u, b1_ = (t>>1)&1u, b2_ = (t>>2)&1u, b3_ = (t>>3)&1u,
                   b4_ = (t>>4)&1u, b5_ = (t>>5)&1u, b6_ = (t>>6)&1u, b7_ = (t>>7)&1u;
    const unsigned P7 = b7_, P6 = P7^b6_, P5 = P6^b5_, P4 = P5^b4_,
                   P3 = P4^b3_, P2 = P3^b2_, P1 = P2^b1_, T = P1^b0_;  // Pk = parity(t>>k)
    const unsigned base_j = ((T ^ b7_) << 11) | (P6 << 10) | (P5 << 9) | (P4 << 8)
                          | (P3 << 7) | (P2 << 6) | (P1 << 5) | (T << 4)
                          | (T ? 0xFu : 0u);
    const unsigned rA = (base_j >> 8) & 15u;
    const unsigned tA = base_j & 255u;
    const unsigned baseCA = (rA << 8) | ((tA ^ (tA >> 4)) ^ (rA * 17u));

    // Gates in ascending bit order (1,2,4,8): first gate after a transition
    // needs only a[0],a[1]. Bit (1<<g) -> gm[base+3-g].
    #define STAGE(base) \
        _Pragma("unroll") \
        for (int g = 0; g < 4; ++g) { \
            const v2f* cp = (const v2f*)gm[(base) + 3 - g]; \
            const v2f c0=cp[0],c1=cp[1],c2=cp[2],c3=cp[3], \
                      c4=cp[4],c5=cp[5],c6=cp[6],c7=cp[7]; \
            const int bit = 1 << g; \
            _Pragma("unroll") \
            for (int r0 = 0; r0 < 16; ++r0) \
                if (!(r0 & bit)) bfly(a[r0], a[r0|bit], c0,c1,c2,c3,c4,c5,c6,c7); \
        }

    int pb = 0;  // staging buffer parity (folds under full unroll)
    #pragma unroll
    for (int l = 0; l < NL; ++l) {
        // ---- stage 0: qubits 0..3 ----
        STAGE(l*12)
        // ---- transition A->B (single barrier, double-buffered) ----
        {
            v2f* bp = buf[pb]; pb ^= 1;
            #pragma unroll
            for (int r = 0; r < 16; ++r) bp[vAB ^ (r*17)] = a[r];
            __syncthreads();
            #pragma unroll
            for (int r = 0; r < 16; ++r) a[r] = bp[(r<<8) | (phit ^ (r*17))];
        }

        // ---- stage 1: qubits 4..7 ----
        STAGE(l*12 + 4)
        // ---- transition B->C ----
        {
            v2f* bp = buf[pb]; pb ^= 1;
            #pragma unroll
            for (int r = 0; r < 16; ++r) bp[wBC ^ r] = a[r];
            __syncthreads();
            #pragma unroll
            for (int r = 0; r < 16; ++r) a[r] = bp[(r<<8) | (phit ^ (r*17))];
        }

        // ---- stage 2: qubits 8..11 ----
        STAGE(l*12 + 8)
        if (l < NL-1) {
            // ---- transition C->A' with ring-CNOT permutation fused ----
            v2f* bp = buf[pb]; pb ^= 1;
            #pragma unroll
            for (int r = 0; r < 16; ++r) {
                const unsigned k3 = (r>>3)&1u;
                const unsigned k2 = k3 ^ ((r>>2)&1u);
                const unsigned k1 = k2 ^ ((r>>1)&1u);
                const unsigned k0 = k1 ^ (r&1u);           // = par(r)
                const unsigned K  = (k3<<3)|(k2<<2)|(k1<<1)|k0;
                const unsigned d  = K ^ (k0 * 0x888u);     // compile-time per r
                bp[baseCA ^ d] = a[r];
            }
            __syncthreads();
            #pragma unroll
            for (int r = 0; r < 16; ++r) a[r] = bp[(r<<8) | (phit ^ (r*17))];
        }
    }

    // ---- readout: signs are bits of j = M(i), i = (t<<4)|r ----
    const float S0 = (T ^ b7_) ? -1.f : 1.f;  // j_11 base (flip by par(r))
    const float S1 = P6 ? -1.f : 1.f;         // j_10
    const float S2 = P5 ? -1.f : 1.f;         // j_9
    const float S3 = P4 ? -1.f : 1.f;         // j_8
    const float S4 = P3 ? -1.f : 1.f;         // j_7
    const float S5 = P2 ? -1.f : 1.f;         // j_6
    const float S6 = P1 ? -1.f : 1.f;         // j_5
    const float S7 = T  ? -1.f : 1.f;         // j_4
    const float S8 = T  ? -1.f : 1.f;         // j_3 base (flip by r3)
    const float S9 = T  ? -1.f : 1.f;         // j_2 base (flip by r3^r2)

    float acc[NC];
    #pragma unroll
    for (int c = 0; c < NC; ++c) acc[c] = 0.f;
    #pragma unroll
    for (int r = 0; r < 16; ++r) {
        const float p = a[r].x*a[r].x + a[r].y*a[r].y;
        const int r3 = (r>>3)&1, r2 = (r>>2)&1, r1 = (r>>1)&1, r0b = r&1;
        const int par = r3 ^ r2 ^ r1 ^ r0b;
        acc[0] += (par        ? -S0 : S0) * p;
        acc[1] += S1 * p;
        acc[2] += S2 * p;
        acc[3] += S3 * p;
        acc[4] += S4 * p;
        acc[5] += S5 * p;
        acc[6] += S6 * p;
        acc[7] += S7 * p;
        acc[8] += (r3         ? -S8 : S8) * p;
        acc[9] += ((r3 ^ r2)  ? -S9 : S9) * p;
    }
    #pragma unroll
    for (int off = 32; off >= 1; off >>= 1) {
        #pragma unroll
        for (int c = 0; c < NC; ++c)
            acc[c] += __shfl_down(acc[c], off, 64);
    }
    const int wave = t >> 6, lane = t & 63;
    if (lane == 0) {
        #pragma unroll
        for (int c = 0; c < NC; ++c) red[wave*NC + c] = acc[c];
    }
    __syncthreads();
    if (t == 0) {
        float ez[NC];
        float mx = -1e30f;
        #pragma unroll
        for (int c = 0; c < NC; ++c) {
            ez[c] = red[c] + red[NC + c] + red[2*NC + c] + red[3*NC + c] + bias[c];
            mx = fmaxf(mx, ez[c]);
        }
        float sum = 0.f;
        #pragma unroll
        for (int c = 0; c < NC; ++c) { ez[c] = expf(ez[c] - mx); sum += ez[c]; }
        const float inv = 1.f / sum;
        #pragma unroll
        for (int c = 0; c < NC; ++c) probs[b*NC + c] = ez[c] * inv;
        // release: make this row visible device-wide, then announce arrival
        __threadfence();
        const unsigned old = atomicAdd(cnt, 1u);
        sh_last = ((old & (NB - 1u)) == (NB - 1u)) ? 1 : 0;
    }
    __syncthreads();
    if (!sh_last) return;

    // ================= BatchNorm (training mode), last block only ==========
    __threadfence();   // acquire: all 512 rows visible (atomic total order)
    float v0[NC], v1[NC];
    #pragma unroll
    for (int c = 0; c < NC; ++c) {
        v0[c] = probs[t*NC + c];
        v1[c] = probs[(t + 256)*NC + c];
    }
    float s[NC], ss[NC];
    #pragma unroll
    for (int c = 0; c < NC; ++c) {
        s[c]  = v0[c] + v1[c];
        ss[c] = v0[c]*v0[c] + v1[c]*v1[c];
    }
    #pragma unroll
    for (int off = 32; off >= 1; off >>= 1) {
        #pragma unroll
        for (int c = 0; c < NC; ++c) {
            s[c]  += __shfl_down(s[c],  off, 64);
            ss[c] += __shfl_down(ss[c], off, 64);
        }
    }
    __syncthreads();   // red[] reuse: readout consumers are done
    if (lane == 0) {
        #pragma unroll
        for (int c = 0; c < NC; ++c) {
            red[wave*20 + c]      = s[c];
            red[wave*20 + NC + c] = ss[c];
        }
    }
    __syncthreads();
    if (t < NC) {
        const float S  = red[t]      + red[20 + t]      + red[40 + t]      + red[60 + t];
        const float SS = red[NC + t] + red[20 + NC + t] + red[40 + NC + t] + red[60 + NC + t];
        const float mu  = S * (1.f/512.f);
        const float var = SS * (1.f/512.f) - mu*mu;
        stats[t]      = mu;
        stats[NC + t] = 1.f / sqrtf(var + BN_EPS);
    }
    __syncthreads();
    #pragma unroll
    for (int c = 0; c < NC; ++c) {
        const float mu = stats[c], inv = stats[NC + c];
        const float g = gamma[c], bt = beta[c];
        probs[t*NC + c]         = (v0[c] - mu) * inv * g + bt;
        probs[(t + 256)*NC + c] = (v1[c] - mu) * inv * g + bt;
    }
}

extern "C" void kernel_launch(void* const* d_in, const int* in_sizes, int n_in,
                              void* d_out, int out_size, void* d_ws, size_t ws_size,
                              hipStream_t stream) {
    const float* x     = (const float*)d_in[0];   // (512, 12)
    const float* w     = (const float*)d_in[1];   // (4, 12, 3)
    const float* bias  = (const float*)d_in[2];   // (10,)
    const float* gamma = (const float*)d_in[3];   // (10,)
    const float* beta  = (const float*)d_in[4];   // (10,)
    float* out    = (float*)d_out;                // (512, 10) float32
    unsigned* cnt = (unsigned*)d_ws;              // arrival counter (any init ok)

    vqc_kernel<<<NB, 256, 0, stream>>>(x, w, bias, gamma, beta, out, cnt);
}

// Round 9
// 85.431 us; speedup vs baseline: 1.0796x; 1.0664x over previous
//
#include <hip/hip_runtime.h>
#include <math.h>

#define NQ 12
#define NL 4
#define NC 10
#define NB 512
#define BN_EPS 1e-5f

typedef float v2f __attribute__((ext_vector_type(2)));

// Packed complex 2x2 butterfly. Constants pre-paired:
// c0={m0,m0} c1={-m1,m1} c2={m2,m2} c3={-m3,m3} (row 0), c4..c7 row 1.
__device__ __forceinline__ void bfly(v2f& A, v2f& B,
    v2f c0, v2f c1, v2f c2, v2f c3, v2f c4, v2f c5, v2f c6, v2f c7)
{
    const v2f As = A.yx, Bs = B.yx;
    const v2f An = __builtin_elementwise_fma(c0, A,
                   __builtin_elementwise_fma(c1, As,
                   __builtin_elementwise_fma(c2, B, c3 * Bs)));
    const v2f Bn = __builtin_elementwise_fma(c4, A,
                   __builtin_elementwise_fma(c5, As,
                   __builtin_elementwise_fma(c6, B, c7 * Bs)));
    A = An; B = Bn;
}

// Register-tiled VQC (round-5 configuration, best measured: 86.1 us total).
// One block per sample; 16 amps (4 local qubits) per thread; 11 double-
// buffered single-barrier transitions; gm in LDS; ring-CNOT fused into
// C->A' write addresses + readout signs.
__global__ __launch_bounds__(256) void vqc_kernel(
    const float* __restrict__ x, const float* __restrict__ w,
    const float* __restrict__ bias, float* __restrict__ probs)
{
    __shared__ v2f buf[2][4096];                  // 2 x 32 KB staging
    __shared__ __align__(16) float gm[48][16];    // 48 gates x 8 paired consts
    __shared__ float red[4*NC];

    const int b = blockIdx.x;
    const int t = threadIdx.x;

    // ---- one-time: all 48 fused (Rot * RY) matrices, pre-paired/negated ----
    if (t < 48) {
        const int l = t / NQ, q = t % NQ;
        const float xq = 0.5f * x[b*NQ + q];
        const float cx = cosf(xq), sx = sinf(xq);
        const int wi = (l*NQ + q)*3;
        const float phi = w[wi], tht = w[wi+1], om = w[wi+2];
        const float ct = cosf(0.5f*tht), st = sinf(0.5f*tht);
        const float aa = 0.5f*(phi + om), dd = 0.5f*(phi - om);
        const float ca = cosf(aa), sa = sinf(aa);
        const float cd = cosf(dd), sd = sinf(dd);
        const float u00r =  ca*ct, u00i = -sa*ct;
        const float u01r = -cd*st, u01i = -sd*st;
        const float u10r =  cd*st, u10i = -sd*st;
        const float u11r =  ca*ct, u11i =  sa*ct;
        const float m00r = u00r*cx + u01r*sx, m00i = u00i*cx + u01i*sx;
        const float m01r = u01r*cx - u00r*sx, m01i = u01i*cx - u00i*sx;
        const float m10r = u10r*cx + u11r*sx, m10i = u10i*cx + u11i*sx;
        const float m11r = u11r*cx - u10r*sx, m11i = u11i*cx - u10i*sx;
        float* gp = gm[t];
        gp[0]  =  m00r; gp[1]  = m00r;
        gp[2]  = -m00i; gp[3]  = m00i;
        gp[4]  =  m01r; gp[5]  = m01r;
        gp[6]  = -m01i; gp[7]  = m01i;
        gp[8]  =  m10r; gp[9]  = m10r;
        gp[10] = -m10i; gp[11] = m10i;
        gp[12] =  m11r; gp[13] = m11r;
        gp[14] = -m11i; gp[15] = m11i;
    }
    __syncthreads();

    // ---- registers: stage-A layout, global i = (r<<8)|t ----
    v2f a[16];
    #pragma unroll
    for (int r = 0; r < 16; ++r) a[r] = (v2f){0.f, 0.f};
    if (t == 0) a[0].x = 1.f;

    const int tl = t & 15, th4 = t >> 4;
    const int phit = t ^ th4;                       // phi(t)
    const int vAB = (th4 << 8) | (tl ^ (th4 * 17)); // A->B write base
    const int wBC = (tl << 8) | ((th4 ^ tl) * 17);  // B->C write base

    // ---- C->A' (CNOT ring) per-thread constants ----
    const unsigned b0_ = t & 1u, b1_ = (t>>1)&1u, b2_ = (t>>2)&1u, b3_ = (t>>3)&1u,
                   b4_ = (t>>4)&1u, b5_ = (t>>5)&1u, b6_ = (t>>6)&1u, b7_ = (t>>7)&1u;
    const unsigned P7 = b7_, P6 = P7^b6_, P5 = P6^b5_, P4 = P5^b4_,
                   P3 = P4^b3_, P2 = P3^b2_, P1 = P2^b1_, T = P1^b0_;  // Pk = parity(t>>k)
    const unsigned base_j = ((T ^ b7_) << 11) | (P6 << 10) | (P5 << 9) | (P4 << 8)
                          | (P3 << 7) | (P2 << 6) | (P1 << 5) | (T << 4)
                          | (T ? 0xFu : 0u);
    const unsigned rA = (base_j >> 8) & 15u;
    const unsigned tA = base_j & 255u;
    const unsigned baseCA = (rA << 8) | ((tA ^ (tA >> 4)) ^ (rA * 17u));

    // Gates in ascending bit order (1,2,4,8): first gate after a transition
    // needs only a[0],a[1]. Bit (1<<g) -> gm[base+3-g].
    #define STAGE(base) \
        _Pragma("unroll") \
        for (int g = 0; g < 4; ++g) { \
            const v2f* cp = (const v2f*)gm[(base) + 3 - g]; \
            const v2f c0=cp[0],c1=cp[1],c2=cp[2],c3=cp[3], \
                      c4=cp[4],c5=cp[5],c6=cp[6],c7=cp[7]; \
            const int bit = 1 << g; \
            _Pragma("unroll") \
            for (int r0 = 0; r0 < 16; ++r0) \
                if (!(r0 & bit)) bfly(a[r0], a[r0|bit], c0,c1,c2,c3,c4,c5,c6,c7); \
        }

    int pb = 0;  // staging buffer parity (folds under full unroll)
    #pragma unroll
    for (int l = 0; l < NL; ++l) {
        // ---- stage 0: qubits 0..3 ----
        STAGE(l*12)
        // ---- transition A->B (single barrier, double-buffered) ----
        {
            v2f* bp = buf[pb]; pb ^= 1;
            #pragma unroll
            for (int r = 0; r < 16; ++r) bp[vAB ^ (r*17)] = a[r];
            __syncthreads();
            #pragma unroll
            for (int r = 0; r < 16; ++r) a[r] = bp[(r<<8) | (phit ^ (r*17))];
        }

        // ---- stage 1: qubits 4..7 ----
        STAGE(l*12 + 4)
        // ---- transition B->C ----
        {
            v2f* bp = buf[pb]; pb ^= 1;
            #pragma unroll
            for (int r = 0; r < 16; ++r) bp[wBC ^ r] = a[r];
            __syncthreads();
            #pragma unroll
            for (int r = 0; r < 16; ++r) a[r] = bp[(r<<8) | (phit ^ (r*17))];
        }

        // ---- stage 2: qubits 8..11 ----
        STAGE(l*12 + 8)
        if (l < NL-1) {
            // ---- transition C->A' with ring-CNOT permutation fused ----
            v2f* bp = buf[pb]; pb ^= 1;
            #pragma unroll
            for (int r = 0; r < 16; ++r) {
                const unsigned k3 = (r>>3)&1u;
                const unsigned k2 = k3 ^ ((r>>2)&1u);
                const unsigned k1 = k2 ^ ((r>>1)&1u);
                const unsigned k0 = k1 ^ (r&1u);           // = par(r)
                const unsigned K  = (k3<<3)|(k2<<2)|(k1<<1)|k0;
                const unsigned d  = K ^ (k0 * 0x888u);     // compile-time per r
                bp[baseCA ^ d] = a[r];
            }
            __syncthreads();
            #pragma unroll
            for (int r = 0; r < 16; ++r) a[r] = bp[(r<<8) | (phit ^ (r*17))];
        }
    }

    // ---- readout: signs are bits of j = M(i), i = (t<<4)|r ----
    const float S0 = (T ^ b7_) ? -1.f : 1.f;  // j_11 base (flip by par(r))
    const float S1 = P6 ? -1.f : 1.f;         // j_10
    const float S2 = P5 ? -1.f : 1.f;         // j_9
    const float S3 = P4 ? -1.f : 1.f;         // j_8
    const float S4 = P3 ? -1.f : 1.f;         // j_7
    const float S5 = P2 ? -1.f : 1.f;         // j_6
    const float S6 = P1 ? -1.f : 1.f;         // j_5
    const float S7 = T  ? -1.f : 1.f;         // j_4
    const float S8 = T  ? -1.f : 1.f;         // j_3 base (flip by r3)
    const float S9 = T  ? -1.f : 1.f;         // j_2 base (flip by r3^r2)

    float acc[NC];
    #pragma unroll
    for (int c = 0; c < NC; ++c) acc[c] = 0.f;
    #pragma unroll
    for (int r = 0; r < 16; ++r) {
        const float p = a[r].x*a[r].x + a[r].y*a[r].y;
        const int r3 = (r>>3)&1, r2 = (r>>2)&1, r1 = (r>>1)&1, r0b = r&1;
        const int par = r3 ^ r2 ^ r1 ^ r0b;
        acc[0] += (par        ? -S0 : S0) * p;
        acc[1] += S1 * p;
        acc[2] += S2 * p;
        acc[3] += S3 * p;
        acc[4] += S4 * p;
        acc[5] += S5 * p;
        acc[6] += S6 * p;
        acc[7] += S7 * p;
        acc[8] += (r3         ? -S8 : S8) * p;
        acc[9] += ((r3 ^ r2)  ? -S9 : S9) * p;
    }
    #pragma unroll
    for (int off = 32; off >= 1; off >>= 1) {
        #pragma unroll
        for (int c = 0; c < NC; ++c)
            acc[c] += __shfl_down(acc[c], off, 64);
    }
    const int wave = t >> 6, lane = t & 63;
    if (lane == 0) {
        #pragma unroll
        for (int c = 0; c < NC; ++c) red[wave*NC + c] = acc[c];
    }
    __syncthreads();
    if (t == 0) {
        float ez[NC];
        float mx = -1e30f;
        #pragma unroll
        for (int c = 0; c < NC; ++c) {
            ez[c] = red[c] + red[NC + c] + red[2*NC + c] + red[3*NC + c] + bias[c];
            mx = fmaxf(mx, ez[c]);
        }
        float sum = 0.f;
        #pragma unroll
        for (int c = 0; c < NC; ++c) { ez[c] = expf(ez[c] - mx); sum += ez[c]; }
        const float inv = 1.f / sum;
        #pragma unroll
        for (int c = 0; c < NC; ++c) probs[b*NC + c] = ez[c] * inv;
    }
}

// BatchNorm1d (training mode, biased var) over the batch dim, in place on d_out.
__global__ __launch_bounds__(256) void bn_kernel(
    float* __restrict__ probs, const float* __restrict__ gamma,
    const float* __restrict__ beta)
{
    const int c = blockIdx.x;
    const int t = threadIdx.x;
    const float v0 = probs[t*NC + c];
    const float v1 = probs[(t + 256)*NC + c];
    float s  = v0 + v1;
    float ss = v0*v0 + v1*v1;
    #pragma unroll
    for (int off = 32; off >= 1; off >>= 1) {
        s  += __shfl_down(s,  off, 64);
        ss += __shfl_down(ss, off, 64);
    }
    __shared__ float sm[8];
    __shared__ float stat[2];
    const int wave = t >> 6, lane = t & 63;
    if (lane == 0) { sm[wave] = s; sm[4 + wave] = ss; }
    __syncthreads();
    if (t == 0) {
        const float S  = sm[0] + sm[1] + sm[2] + sm[3];
        const float SS = sm[4] + sm[5] + sm[6] + sm[7];
        const float mu  = S * (1.f/512.f);
        const float var = SS * (1.f/512.f) - mu*mu;
        stat[0] = mu;
        stat[1] = 1.f / sqrtf(var + BN_EPS);
    }
    __syncthreads();
    const float mu = stat[0], inv = stat[1];
    const float g = gamma[c], bt = beta[c];
    probs[t*NC + c]         = (v0 - mu) * inv * g + bt;
    probs[(t + 256)*NC + c] = (v1 - mu) * inv * g + bt;
}

extern "C" void kernel_launch(void* const* d_in, const int* in_sizes, int n_in,
                              void* d_out, int out_size, void* d_ws, size_t ws_size,
                              hipStream_t stream) {
    const float* x     = (const float*)d_in[0];   // (512, 12)
    const float* w     = (const float*)d_in[1];   // (4, 12, 3)
    const float* bias  = (const float*)d_in[2];   // (10,)
    const float* gamma = (const float*)d_in[3];   // (10,)
    const float* beta  = (const float*)d_in[4];   // (10,)
    float* out = (float*)d_out;                   // (512, 10) float32

    vqc_kernel<<<NB, 256, 0, stream>>>(x, w, bias, out);
    bn_kernel<<<NC, 256, 0, stream>>>(out, gamma, beta);
}